// Round 14
// baseline (311.356 us; speedup 1.0000x reference)
//
#include <hip/hip_runtime.h>
#include <hip/hip_bf16.h>
#include <math.h>

#define Bb 8
#define Nn 400
#define GN 2
#define INF 66        // INPUT_DIM + HIDDEN
#define IDIM 330      // logical K
#define KP 352        // K padded to 32
#define HID 64
#define EMB 16
#define NKP 416       // node-dim padded to 32
#define XTR 80        // XT rows (66 cols padded to 80)
constexpr int M = Bb * Nn;   // 3200 nodes

typedef __attribute__((ext_vector_type(8))) short short8;   // 8 x bf16 frag
typedef __attribute__((ext_vector_type(4))) float f32x4;

__device__ __forceinline__ ushort f2bf(float f) {
    union { float f; unsigned u; } v; v.f = f;
    unsigned u = v.u;
    unsigned r = (u + 0x7FFFu + ((u >> 16) & 1u)) >> 16;
    return (ushort)r;
}
__device__ __forceinline__ float bf2f(ushort u) {
    union { unsigned u; float f; } v; v.u = (unsigned)u << 16;
    return v.f;
}

// ================= prep: gconv(vec4) | wT(gates) | wT(cand) | concat =================
// grid 1-D: [0,2600) gconv, [2600,3128) wT, [3128,3184) concat
#define GBLKS4 2600
__global__ void k_prep(const float* __restrict__ G, const float* __restrict__ Wg,
                       const float* __restrict__ Wc, const float* __restrict__ x,
                       const float* __restrict__ state,
                       ushort* __restrict__ Gbf, ushort* __restrict__ WgT,
                       ushort* __restrict__ WcT, ushort* __restrict__ Hbf,
                       ushort* __restrict__ XTin, int* __restrict__ cnt) {
    __shared__ float Tw[32][65];
    __shared__ ushort Tc[64][XTR + 1];
    int bid = blockIdx.x;
    if (bid == 0 && threadIdx.x < 32) cnt[threadIdx.x] = 0;   // hop sync counters
    if (bid < GBLKS4) {
        size_t tid4 = ((size_t)bid * 256 + threadIdx.x) * 4;
        int k = (int)(tid4 % NKP);
        size_t row = tid4 / NKP;
        ushort4 o;
        if (k < Nn) {
            float4 gv = *(const float4*)(G + row * Nn + k);
            o.x = f2bf(gv.x); o.y = f2bf(gv.y); o.z = f2bf(gv.z); o.w = f2bf(gv.w);
        } else {
            o.x = o.y = o.z = o.w = 0;
        }
        *(ushort4*)(Gbf + tid4) = o;
        return;
    }
    bid -= GBLKS4;
    if (bid < 352 + 176) {
        const float* W; ushort* WT; int O;
        if (bid < 352) { W = Wg; WT = WgT; O = 128; }
        else           { bid -= 352; W = Wc; WT = WcT; O = 64; }
        const int k0 = (bid % 11) * 32;
        const int c0 = (bid / 11) * 64;
        const int d = c0 / O, o0 = c0 % O;
        for (int e = threadIdx.x; e < 2048; e += 256) {
            int kk = e >> 6, oo = e & 63;
            int k = k0 + kk;
            Tw[kk][oo] = (k < IDIM) ? W[((size_t)d * IDIM + k) * O + o0 + oo] : 0.f;
        }
        __syncthreads();
        for (int e = threadIdx.x; e < 2048; e += 256) {
            int cc = e >> 5, kk = e & 31;
            WT[(size_t)(c0 + cc) * KP + k0 + kk] = f2bf(Tw[kk][cc]);
        }
        return;
    }
    bid -= 528;
    const int b = bid / 7;
    const int k0 = (bid % 7) * 64;
    for (int e = threadIdx.x; e < 64 * XTR; e += 256) {
        int kk = e / XTR, c = e % XTR;
        int k = k0 + kk;
        ushort bf = 0;
        if (k < Nn && c < INF) {
            float v = (c < 2) ? x[((size_t)b * Nn + k) * 2 + c]
                              : state[((size_t)b * Nn + k) * HID + c - 2];
            bf = f2bf(v);
            Hbf[((size_t)b * Nn + k) * KP + c] = bf;
        }
        Tc[kk][c] = bf;
    }
    for (int e = threadIdx.x; e < 64 * 22; e += 256) {
        int kk = e / 22, c = 330 + e % 22;
        int k = k0 + kk;
        if (k < Nn) Hbf[((size_t)b * Nn + k) * KP + c] = 0;
    }
    __syncthreads();
    for (int e = threadIdx.x; e < XTR * 64; e += 256) {
        int c = e / 64, kk = e % 64;
        int k = k0 + kk;
        if (k < NKP) XTin[((size_t)b * XTR + c) * NKP + k] = Tc[kk][c];
    }
}

// ================= hop core (round-5 proven math, as device function) =================
__device__ __forceinline__ void hop_core(const ushort* __restrict__ Gb,
        const ushort* __restrict__ Xb, ushort* __restrict__ Hout,
        ushort* __restrict__ Xn, int row0) {
    const int lane = threadIdx.x;
    const int lr = lane & 15, kq = lane >> 4;
    const ushort* Grow = Gb + (size_t)(row0 + lr) * NKP;   // row0+lr <= 399

    f32x4 acc[5] = {};
#pragma unroll
    for (int ks = 0; ks < 13; ++ks) {
        short8 af = *(const short8*)(Grow + ks * 32 + kq * 8);
#pragma unroll
        for (int n = 0; n < 5; ++n) {
            short8 bv = *(const short8*)(Xb + (size_t)(n * 16 + lr) * NKP + ks * 32 + kq * 8);
            acc[n] = __builtin_amdgcn_mfma_f32_16x16x32_bf16(af, bv, acc[n], 0, 0, 0);
        }
    }

    const int rbase = row0 + kq * 4;   // <= 396
#pragma unroll
    for (int n = 0; n < 5; ++n) {
        int col = n * 16 + lr;
        if (col < INF) {
#pragma unroll
            for (int r = 0; r < 4; ++r)
                Hout[(size_t)(rbase + r) * KP + col] = f2bf(acc[n][r]);
        }
    }
    if (Xn) {
#pragma unroll
        for (int n = 0; n < 5; ++n) {
            int col = n * 16 + lr;
            ushort4 w;
#pragma unroll
            for (int r = 0; r < 4; ++r)
                w[r] = (col < INF) ? f2bf(acc[n][r]) : (ushort)0;
            *(ushort4*)(Xn + (size_t)col * NKP + rbase) = w;
        }
    }
}

// ================= merged hop0+hop1: grid (50, B, GN), block 64 =================
// blocks x<25: hop0 (produce XTmid[g][b], release-count). blocks x>=25: hop1
// (acquire-spin until 25 producers of (g,b) done, then consume XTmid).
// Deadlock-safe: 800 single-wave blocks << device wave capacity.
__global__ __launch_bounds__(64) void k_hop2(const ushort* __restrict__ Gbf,
        const ushort* __restrict__ XTin, ushort* __restrict__ Hb,
        ushort* __restrict__ XTmid, int* __restrict__ cnt) {
    const int b = blockIdx.y, g = blockIdx.z;
    const ushort* Gb = Gbf + (size_t)(g * Bb + b) * Nn * NKP;
    ushort* Hbb = Hb + (size_t)b * Nn * KP;
    ushort* Xm = XTmid + (size_t)(g * Bb + b) * XTR * NKP;
    int* c = cnt + g * Bb + b;

    if (blockIdx.x < 25) {
        hop_core(Gb, XTin + (size_t)b * XTR * NKP, Hbb + 66 + g * 132, Xm,
                 blockIdx.x * 16);
        __threadfence();
        if (threadIdx.x == 0)
            __hip_atomic_fetch_add(c, 1, __ATOMIC_RELEASE, __HIP_MEMORY_SCOPE_AGENT);
    } else {
        if (threadIdx.x == 0) {
            while (__hip_atomic_load(c, __ATOMIC_ACQUIRE, __HIP_MEMORY_SCOPE_AGENT) < 25)
                __builtin_amdgcn_s_sleep(8);
        }
        __threadfence();
        hop_core(Gb, Xm, Hbb + 132 + g * 132, nullptr, (blockIdx.x - 25) * 16);
    }
}

// ================= gemm1: dsplit=16, 1 d per block, grid (16,50) = 800 blocks =================
// BM=64, BN=128. 4 waves 2x2. Double-buffered LDS + register prefetch, one barrier
// per K-step. Writes e-scaled BF16 partials P[d][m][o].
__global__ __launch_bounds__(256, 4) void k_meta_d16(const ushort* __restrict__ Hbf,
        const ushort* __restrict__ WT, const float* __restrict__ emb,
        ushort* __restrict__ P) {
    constexpr int O = 128;
    __shared__ ushort As[2][64][40];
    __shared__ ushort Bs[2][O][40];
    const int d = blockIdx.x;       // 0..15
    const int bm = blockIdx.y * 64;
    const int t = threadIdx.x;
    const int wid = t >> 6, lane = t & 63;
    const int wm = wid >> 1, wn = wid & 1;
    const int lr = lane & 15, kq = lane >> 4;

    const int ar = t >> 2, akc = (t & 3) * 8;
    const ushort* srcA = Hbf + (size_t)(bm + ar) * KP + akc;
    int brow[2], bkc[2];
    const ushort* srcB[2];
#pragma unroll
    for (int p = 0; p < 2; ++p) {
        int chunk = t + p * 256;
        brow[p] = chunk >> 2; bkc[p] = (chunk & 3) * 8;
        srcB[p] = WT + ((size_t)d * O + brow[p]) * KP + bkc[p];
    }

    short8 ra, rb[2];
    ra = *(const short8*)srcA;
#pragma unroll
    for (int p = 0; p < 2; ++p) rb[p] = *(const short8*)srcB[p];

    f32x4 seg[2][4] = {};   // [m][n]

    for (int ks = 0; ks < 11; ++ks) {
        const int buf = ks & 1;
        *(short8*)&As[buf][ar][akc] = ra;
#pragma unroll
        for (int p = 0; p < 2; ++p) *(short8*)&Bs[buf][brow[p]][bkc[p]] = rb[p];
        if (ks < 10) {
            const int k0 = (ks + 1) * 32;
            ra = *(const short8*)(srcA + k0);
#pragma unroll
            for (int p = 0; p < 2; ++p) rb[p] = *(const short8*)(srcB[p] + k0);
        }
        __syncthreads();
        short8 a[2], bf[4];
#pragma unroll
        for (int m = 0; m < 2; ++m)
            a[m] = *(const short8*)&As[buf][wm * 32 + m * 16 + lr][kq * 8];
#pragma unroll
        for (int n = 0; n < 4; ++n)
            bf[n] = *(const short8*)&Bs[buf][wn * 64 + n * 16 + lr][kq * 8];
#pragma unroll
        for (int m = 0; m < 2; ++m)
#pragma unroll
            for (int n = 0; n < 4; ++n)
                seg[m][n] = __builtin_amdgcn_mfma_f32_16x16x32_bf16(a[m], bf[n], seg[m][n], 0, 0, 0);
    }

    ushort* Pd = P + (size_t)d * M * O;
#pragma unroll
    for (int m = 0; m < 2; ++m) {
        const int rbase = bm + wm * 32 + m * 16 + kq * 4;
#pragma unroll
        for (int r = 0; r < 4; ++r) {
            const int row = rbase + r;
            float e0 = emb[(size_t)row * EMB + d];
#pragma unroll
            for (int n = 0; n < 4; ++n) {
                const int col = wn * 64 + n * 16 + lr;
                Pd[(size_t)row * O + col] = f2bf(e0 * seg[m][n][r]);
            }
        }
    }
}

// ================= gemm2: dsplit=8 (2 d's share A), grid (8,50) — bf16 partials =================
template <int O>
__global__ __launch_bounds__(256, 3) void k_meta_fused(const ushort* __restrict__ Hbf,
        const ushort* __restrict__ WT, const float* __restrict__ emb,
        ushort* __restrict__ P) {
    constexpr int NB = O / 32;
    constexpr int PB = O / 64;
    __shared__ ushort As[2][64][40];
    __shared__ ushort Bs[2][2][O][40];
    const int ds = blockIdx.x;
    const int bm = blockIdx.y * 64;
    const int t = threadIdx.x;
    const int wid = t >> 6, lane = t & 63;
    const int wm = wid >> 1, wn = wid & 1;
    const int lr = lane & 15, kq = lane >> 4;

    const int ar = t >> 2, akc = (t & 3) * 8;
    const ushort* srcA = Hbf + (size_t)(bm + ar) * KP + akc;
    const ushort* srcB[2][PB];
    int brow[PB], bkc[PB];
#pragma unroll
    for (int p = 0; p < PB; ++p) {
        int chunk = t + p * 256;
        brow[p] = chunk >> 2; bkc[p] = (chunk & 3) * 8;
#pragma unroll
        for (int j = 0; j < 2; ++j)
            srcB[j][p] = WT + ((size_t)(ds * 2 + j) * O + brow[p]) * KP + bkc[p];
    }

    short8 ra, rb[2][PB];
    ra = *(const short8*)srcA;
#pragma unroll
    for (int j = 0; j < 2; ++j)
#pragma unroll
        for (int p = 0; p < PB; ++p) rb[j][p] = *(const short8*)srcB[j][p];

    f32x4 seg[2][2][NB] = {};

    for (int ks = 0; ks < 11; ++ks) {
        const int buf = ks & 1;
        *(short8*)&As[buf][ar][akc] = ra;
#pragma unroll
        for (int j = 0; j < 2; ++j)
#pragma unroll
            for (int p = 0; p < PB; ++p) *(short8*)&Bs[buf][j][brow[p]][bkc[p]] = rb[j][p];
        if (ks < 10) {
            const int k0 = (ks + 1) * 32;
            ra = *(const short8*)(srcA + k0);
#pragma unroll
            for (int j = 0; j < 2; ++j)
#pragma unroll
                for (int p = 0; p < PB; ++p) rb[j][p] = *(const short8*)(srcB[j][p] + k0);
        }
        __syncthreads();
        short8 a[2], bf[2][NB];
#pragma unroll
        for (int m = 0; m < 2; ++m)
            a[m] = *(const short8*)&As[buf][wm * 32 + m * 16 + lr][kq * 8];
#pragma unroll
        for (int j = 0; j < 2; ++j)
#pragma unroll
            for (int n = 0; n < NB; ++n)
                bf[j][n] = *(const short8*)&Bs[buf][j][wn * (O / 2) + n * 16 + lr][kq * 8];
#pragma unroll
        for (int j = 0; j < 2; ++j)
#pragma unroll
            for (int m = 0; m < 2; ++m)
#pragma unroll
                for (int n = 0; n < NB; ++n)
                    seg[j][m][n] = __builtin_amdgcn_mfma_f32_16x16x32_bf16(a[m], bf[j][n], seg[j][m][n], 0, 0, 0);
    }

    ushort* Pd = P + (size_t)ds * M * O;
#pragma unroll
    for (int m = 0; m < 2; ++m) {
        const int rbase = bm + wm * 32 + m * 16 + kq * 4;
#pragma unroll
        for (int r = 0; r < 4; ++r) {
            const int row = rbase + r;
            float e0 = emb[(size_t)row * EMB + ds * 2];
            float e1 = emb[(size_t)row * EMB + ds * 2 + 1];
#pragma unroll
            for (int n = 0; n < NB; ++n) {
                const int col = wn * (O / 2) + n * 16 + lr;
                Pd[(size_t)row * O + col] = f2bf(e0 * seg[0][m][n][r] + e1 * seg[1][m][n][r]);
            }
        }
    }
}

// ================= z/r: sum 16 bf16 partials + bias + sigmoid; write z, r*state =================
__global__ void k_zr(const ushort* __restrict__ P, const float* __restrict__ emb,
                     const float* __restrict__ bg, const float* __restrict__ state,
                     float* __restrict__ zbuf, ushort* __restrict__ Hbf,
                     ushort* __restrict__ XTin) {
    __shared__ float es[2][EMB];
    const int t = threadIdx.x;
    if (t < 2 * EMB) es[t >> 4][t & 15] = emb[((size_t)blockIdx.x * 2 + (t >> 4)) * EMB + (t & 15)];
    __syncthreads();
    const int node = blockIdx.x * 2 + (t >> 7);
    const int o = t & 127;
    float v = 0.f;
#pragma unroll
    for (int s = 0; s < 16; ++s) v += bf2f(P[((size_t)s * M + node) * 128 + o]);
    const float* e_ = es[t >> 7];
#pragma unroll
    for (int d = 0; d < EMB; ++d) v += e_[d] * bg[d * 128 + o];
    float sg = 1.f / (1.f + expf(-v));
    if (o < 64) {
        zbuf[node * 64 + o] = sg;
    } else {
        int oo = o - 64;
        ushort bf = f2bf(sg * state[node * 64 + oo]);
        Hbf[(size_t)node * KP + 2 + oo] = bf;
        int b = node / Nn, kn = node % Nn;
        XTin[((size_t)b * XTR + 2 + oo) * NKP + kn] = bf;
    }
}

// ================= final: sum 8 bf16 partials + bias + tanh + GRU blend =================
__global__ void k_final(const ushort* __restrict__ P, const float* __restrict__ emb,
                        const float* __restrict__ bc, const float* __restrict__ zbuf,
                        const float* __restrict__ state, float* __restrict__ out) {
    __shared__ float es[4][EMB];
    const int t = threadIdx.x;
    if (t < 4 * EMB) es[t >> 4][t & 15] = emb[((size_t)blockIdx.x * 4 + (t >> 4)) * EMB + (t & 15)];
    __syncthreads();
    const int node = blockIdx.x * 4 + (t >> 6);
    const int o = t & 63;
    float v = 0.f;
#pragma unroll
    for (int s = 0; s < 8; ++s) v += bf2f(P[((size_t)s * M + node) * 64 + o]);
    const float* e_ = es[t >> 6];
#pragma unroll
    for (int d = 0; d < EMB; ++d) v += e_[d] * bc[d * 64 + o];
    float hc = tanhf(v);
    float z = zbuf[node * 64 + o];
    out[node * 64 + o] = z * state[node * 64 + o] + (1.f - z) * hc;
}

extern "C" void kernel_launch(void* const* d_in, const int* in_sizes, int n_in,
                              void* d_out, int out_size, void* d_ws, size_t ws_size,
                              hipStream_t stream) {
    const float* x      = (const float*)d_in[0];
    const float* state  = (const float*)d_in[1];
    const float* graphs = (const float*)d_in[2];
    const float* emb    = (const float*)d_in[3];
    const float* Wg     = (const float*)d_in[4];
    const float* bg     = (const float*)d_in[5];
    const float* Wc     = (const float*)d_in[6];
    const float* bc     = (const float*)d_in[7];
    float* out = (float*)d_out;

    char* ws = (char*)d_ws;
    ushort* Hbf  = (ushort*)ws;  ws += (size_t)M * KP * 2;                 // 2.25 MB
    ushort* Gbf  = (ushort*)ws;  ws += (size_t)GN * Bb * Nn * NKP * 2;     // 5.32 MB
    ushort* WgT  = (ushort*)ws;  ws += (size_t)2048 * KP * 2;              // 1.44 MB
    ushort* WcT  = (ushort*)ws;  ws += (size_t)1024 * KP * 2;              // 0.72 MB
    ushort* XTin = (ushort*)ws;  ws += (size_t)Bb * XTR * NKP * 2;         // 0.53 MB
    ushort* XTmid= (ushort*)ws;  ws += (size_t)GN * Bb * XTR * NKP * 2;    // 1.06 MB
    ushort* PG   = (ushort*)ws;  ws += (size_t)16 * M * 128 * 2;           // 13.1 MB
    ushort* PC   = (ushort*)ws;  ws += (size_t)8 * M * 64 * 2;             // 3.28 MB
    float*  zb   = (float*)ws;   ws += (size_t)M * 64 * 4;                 // 0.82 MB
    int*    cnt  = (int*)ws;                                               // 32 ints

    k_prep<<<3184, 256, 0, stream>>>(graphs, Wg, Wc, x, state, Gbf, WgT, WcT, Hbf, XTin, cnt);

    // ---- first meta_dgcn (gates): merged hop0+hop1, then gemm1, then zr ----
    k_hop2<<<dim3(50, Bb, GN), 64, 0, stream>>>(Gbf, XTin, Hbf, XTmid, cnt);
    k_meta_d16<<<dim3(16, 50), 256, 0, stream>>>(Hbf, WgT, emb, PG);
    k_zr<<<1600, 256, 0, stream>>>(PG, emb, bg, state, zb, Hbf, XTin);

    // ---- second meta_dgcn (candidate): merged hops, gemm2, final ----
    k_hop2<<<dim3(50, Bb, GN), 64, 0, stream>>>(Gbf, XTin, Hbf, XTmid, cnt + 16);
    k_meta_fused<64><<<dim3(8, 50), 256, 0, stream>>>(Hbf, WcT, emb, PC);
    k_final<<<800, 256, 0, stream>>>(PC, emb, bc, zb, state, out);
}

// Round 15
// 71.215 us; speedup vs baseline: 4.3720x; 4.3720x over previous
//
#include <hip/hip_runtime.h>
#include <hip/hip_bf16.h>
#include <math.h>

#define Bb 8
#define Nn 400
#define GN 2
#define INF 66        // INPUT_DIM + HIDDEN
#define IDIM 330      // logical K
#define KP 352        // K padded to 32
#define HID 64
#define EMB 16
#define NKP 416       // node-dim padded to 32
#define XTR 80        // XT rows (66 cols padded to 80)
constexpr int M = Bb * Nn;   // 3200 nodes

typedef __attribute__((ext_vector_type(8))) short short8;   // 8 x bf16 frag
typedef __attribute__((ext_vector_type(4))) float f32x4;

__device__ __forceinline__ ushort f2bf(float f) {
    union { float f; unsigned u; } v; v.f = f;
    unsigned u = v.u;
    unsigned r = (u + 0x7FFFu + ((u >> 16) & 1u)) >> 16;
    return (ushort)r;
}
__device__ __forceinline__ float bf2f(ushort u) {
    union { unsigned u; float f; } v; v.u = (unsigned)u << 16;
    return v.f;
}

// ================= prep: gconv(vec4) | wT(gates) | wT(cand) | concat =================
// grid 1-D: [0,2600) gconv, [2600,3128) wT, [3128,3184) concat
#define GBLKS4 2600
__global__ void k_prep(const float* __restrict__ G, const float* __restrict__ Wg,
                       const float* __restrict__ Wc, const float* __restrict__ x,
                       const float* __restrict__ state,
                       ushort* __restrict__ Gbf, ushort* __restrict__ WgT,
                       ushort* __restrict__ WcT, ushort* __restrict__ Hbf,
                       ushort* __restrict__ XTin) {
    __shared__ float Tw[32][65];
    __shared__ ushort Tc[64][XTR + 1];
    int bid = blockIdx.x;
    if (bid < GBLKS4) {
        size_t tid4 = ((size_t)bid * 256 + threadIdx.x) * 4;
        int k = (int)(tid4 % NKP);
        size_t row = tid4 / NKP;
        ushort4 o;
        if (k < Nn) {
            float4 gv = *(const float4*)(G + row * Nn + k);
            o.x = f2bf(gv.x); o.y = f2bf(gv.y); o.z = f2bf(gv.z); o.w = f2bf(gv.w);
        } else {
            o.x = o.y = o.z = o.w = 0;
        }
        *(ushort4*)(Gbf + tid4) = o;
        return;
    }
    bid -= GBLKS4;
    if (bid < 352 + 176) {
        const float* W; ushort* WT; int O;
        if (bid < 352) { W = Wg; WT = WgT; O = 128; }
        else           { bid -= 352; W = Wc; WT = WcT; O = 64; }
        const int k0 = (bid % 11) * 32;
        const int c0 = (bid / 11) * 64;
        const int d = c0 / O, o0 = c0 % O;
        for (int e = threadIdx.x; e < 2048; e += 256) {
            int kk = e >> 6, oo = e & 63;
            int k = k0 + kk;
            Tw[kk][oo] = (k < IDIM) ? W[((size_t)d * IDIM + k) * O + o0 + oo] : 0.f;
        }
        __syncthreads();
        for (int e = threadIdx.x; e < 2048; e += 256) {
            int cc = e >> 5, kk = e & 31;
            WT[(size_t)(c0 + cc) * KP + k0 + kk] = f2bf(Tw[kk][cc]);
        }
        return;
    }
    bid -= 528;
    const int b = bid / 7;
    const int k0 = (bid % 7) * 64;
    for (int e = threadIdx.x; e < 64 * XTR; e += 256) {
        int kk = e / XTR, c = e % XTR;
        int k = k0 + kk;
        ushort bf = 0;
        if (k < Nn && c < INF) {
            float v = (c < 2) ? x[((size_t)b * Nn + k) * 2 + c]
                              : state[((size_t)b * Nn + k) * HID + c - 2];
            bf = f2bf(v);
            Hbf[((size_t)b * Nn + k) * KP + c] = bf;
        }
        Tc[kk][c] = bf;
    }
    for (int e = threadIdx.x; e < 64 * 22; e += 256) {
        int kk = e / 22, c = 330 + e % 22;
        int k = k0 + kk;
        if (k < Nn) Hbf[((size_t)b * Nn + k) * KP + c] = 0;
    }
    __syncthreads();
    for (int e = threadIdx.x; e < XTR * 64; e += 256) {
        int c = e / 64, kk = e % 64;
        int k = k0 + kk;
        if (k < NKP) XTin[((size_t)b * XTR + c) * NKP + k] = Tc[kk][c];
    }
}

// ================= graph hop via MFMA, LDS-free, 1-wave blocks (round-5 proven) =================
__global__ __launch_bounds__(64) void k_hop(const ushort* __restrict__ Gbf,
                      const ushort* __restrict__ XT,
                      ushort* __restrict__ Hb, ushort* __restrict__ XTnext,
                      int out_base, int xt_per_g) {
    const int b = blockIdx.y, g = blockIdx.z;
    const int row0 = blockIdx.x * 16;
    const int lane = threadIdx.x;
    const int lr = lane & 15, kq = lane >> 4;

    const ushort* Gb = Gbf + (size_t)(g * Bb + b) * Nn * NKP;
    const ushort* Xb = XT + (size_t)((xt_per_g ? g * Bb : 0) + b) * XTR * NKP;
    const ushort* Grow = Gb + (size_t)(row0 + lr) * NKP;

    f32x4 acc[5] = {};
#pragma unroll
    for (int ks = 0; ks < 13; ++ks) {
        short8 af = *(const short8*)(Grow + ks * 32 + kq * 8);
#pragma unroll
        for (int n = 0; n < 5; ++n) {
            short8 bv = *(const short8*)(Xb + (size_t)(n * 16 + lr) * NKP + ks * 32 + kq * 8);
            acc[n] = __builtin_amdgcn_mfma_f32_16x16x32_bf16(af, bv, acc[n], 0, 0, 0);
        }
    }

    const int rbase = row0 + kq * 4;
    ushort* Hout = Hb + (size_t)b * Nn * KP + out_base + g * 132;
#pragma unroll
    for (int n = 0; n < 5; ++n) {
        int col = n * 16 + lr;
        if (col < INF) {
#pragma unroll
            for (int r = 0; r < 4; ++r)
                Hout[(size_t)(rbase + r) * KP + col] = f2bf(acc[n][r]);
        }
    }
    if (XTnext) {
        ushort* Xn = XTnext + (size_t)(g * Bb + b) * XTR * NKP;
#pragma unroll
        for (int n = 0; n < 5; ++n) {
            int col = n * 16 + lr;
            ushort4 w;
#pragma unroll
            for (int r = 0; r < 4; ++r)
                w[r] = (col < INF) ? f2bf(acc[n][r]) : (ushort)0;
            *(ushort4*)(Xn + (size_t)col * NKP + rbase) = w;
        }
    }
}

// ================= gemm1: dsplit=16, 1 d per block, grid (16,50) = 800 blocks =================
// BM=64, BN=128. 4 waves 2x2. Double-buffered LDS + register prefetch, one barrier
// per K-step. Writes e-scaled BF16 partials P[d][m][o] (halves HBM traffic vs fp32).
__global__ __launch_bounds__(256, 4) void k_meta_d16(const ushort* __restrict__ Hbf,
        const ushort* __restrict__ WT, const float* __restrict__ emb,
        ushort* __restrict__ P) {
    constexpr int O = 128;
    __shared__ ushort As[2][64][40];
    __shared__ ushort Bs[2][O][40];
    const int d = blockIdx.x;       // 0..15
    const int bm = blockIdx.y * 64;
    const int t = threadIdx.x;
    const int wid = t >> 6, lane = t & 63;
    const int wm = wid >> 1, wn = wid & 1;
    const int lr = lane & 15, kq = lane >> 4;

    const int ar = t >> 2, akc = (t & 3) * 8;
    const ushort* srcA = Hbf + (size_t)(bm + ar) * KP + akc;
    int brow[2], bkc[2];
    const ushort* srcB[2];
#pragma unroll
    for (int p = 0; p < 2; ++p) {
        int chunk = t + p * 256;
        brow[p] = chunk >> 2; bkc[p] = (chunk & 3) * 8;
        srcB[p] = WT + ((size_t)d * O + brow[p]) * KP + bkc[p];
    }

    short8 ra, rb[2];
    ra = *(const short8*)srcA;
#pragma unroll
    for (int p = 0; p < 2; ++p) rb[p] = *(const short8*)srcB[p];

    f32x4 seg[2][4] = {};   // [m][n]

    for (int ks = 0; ks < 11; ++ks) {
        const int buf = ks & 1;
        *(short8*)&As[buf][ar][akc] = ra;
#pragma unroll
        for (int p = 0; p < 2; ++p) *(short8*)&Bs[buf][brow[p]][bkc[p]] = rb[p];
        if (ks < 10) {
            const int k0 = (ks + 1) * 32;
            ra = *(const short8*)(srcA + k0);
#pragma unroll
            for (int p = 0; p < 2; ++p) rb[p] = *(const short8*)(srcB[p] + k0);
        }
        __syncthreads();
        short8 a[2], bf[4];
#pragma unroll
        for (int m = 0; m < 2; ++m)
            a[m] = *(const short8*)&As[buf][wm * 32 + m * 16 + lr][kq * 8];
#pragma unroll
        for (int n = 0; n < 4; ++n)
            bf[n] = *(const short8*)&Bs[buf][wn * 64 + n * 16 + lr][kq * 8];
#pragma unroll
        for (int m = 0; m < 2; ++m)
#pragma unroll
            for (int n = 0; n < 4; ++n)
                seg[m][n] = __builtin_amdgcn_mfma_f32_16x16x32_bf16(a[m], bf[n], seg[m][n], 0, 0, 0);
    }

    ushort* Pd = P + (size_t)d * M * O;
#pragma unroll
    for (int m = 0; m < 2; ++m) {
        const int rbase = bm + wm * 32 + m * 16 + kq * 4;
#pragma unroll
        for (int r = 0; r < 4; ++r) {
            const int row = rbase + r;
            float e0 = emb[(size_t)row * EMB + d];
#pragma unroll
            for (int n = 0; n < 4; ++n) {
                const int col = wn * 64 + n * 16 + lr;
                Pd[(size_t)row * O + col] = f2bf(e0 * seg[m][n][r]);
            }
        }
    }
}

// ================= gemm2: dsplit=8 (2 d's share A), grid (8,50) — bf16 partials =================
template <int O>
__global__ __launch_bounds__(256, 3) void k_meta_fused(const ushort* __restrict__ Hbf,
        const ushort* __restrict__ WT, const float* __restrict__ emb,
        ushort* __restrict__ P) {
    constexpr int NB = O / 32;
    constexpr int PB = O / 64;
    __shared__ ushort As[2][64][40];
    __shared__ ushort Bs[2][2][O][40];
    const int ds = blockIdx.x;
    const int bm = blockIdx.y * 64;
    const int t = threadIdx.x;
    const int wid = t >> 6, lane = t & 63;
    const int wm = wid >> 1, wn = wid & 1;
    const int lr = lane & 15, kq = lane >> 4;

    const int ar = t >> 2, akc = (t & 3) * 8;
    const ushort* srcA = Hbf + (size_t)(bm + ar) * KP + akc;
    const ushort* srcB[2][PB];
    int brow[PB], bkc[PB];
#pragma unroll
    for (int p = 0; p < PB; ++p) {
        int chunk = t + p * 256;
        brow[p] = chunk >> 2; bkc[p] = (chunk & 3) * 8;
#pragma unroll
        for (int j = 0; j < 2; ++j)
            srcB[j][p] = WT + ((size_t)(ds * 2 + j) * O + brow[p]) * KP + bkc[p];
    }

    short8 ra, rb[2][PB];
    ra = *(const short8*)srcA;
#pragma unroll
    for (int j = 0; j < 2; ++j)
#pragma unroll
        for (int p = 0; p < PB; ++p) rb[j][p] = *(const short8*)srcB[j][p];

    f32x4 seg[2][2][NB] = {};

    for (int ks = 0; ks < 11; ++ks) {
        const int buf = ks & 1;
        *(short8*)&As[buf][ar][akc] = ra;
#pragma unroll
        for (int j = 0; j < 2; ++j)
#pragma unroll
            for (int p = 0; p < PB; ++p) *(short8*)&Bs[buf][j][brow[p]][bkc[p]] = rb[j][p];
        if (ks < 10) {
            const int k0 = (ks + 1) * 32;
            ra = *(const short8*)(srcA + k0);
#pragma unroll
            for (int j = 0; j < 2; ++j)
#pragma unroll
                for (int p = 0; p < PB; ++p) rb[j][p] = *(const short8*)(srcB[j][p] + k0);
        }
        __syncthreads();
        short8 a[2], bf[2][NB];
#pragma unroll
        for (int m = 0; m < 2; ++m)
            a[m] = *(const short8*)&As[buf][wm * 32 + m * 16 + lr][kq * 8];
#pragma unroll
        for (int j = 0; j < 2; ++j)
#pragma unroll
            for (int n = 0; n < NB; ++n)
                bf[j][n] = *(const short8*)&Bs[buf][j][wn * (O / 2) + n * 16 + lr][kq * 8];
#pragma unroll
        for (int j = 0; j < 2; ++j)
#pragma unroll
            for (int m = 0; m < 2; ++m)
#pragma unroll
                for (int n = 0; n < NB; ++n)
                    seg[j][m][n] = __builtin_amdgcn_mfma_f32_16x16x32_bf16(a[m], bf[j][n], seg[j][m][n], 0, 0, 0);
    }

    ushort* Pd = P + (size_t)ds * M * O;
#pragma unroll
    for (int m = 0; m < 2; ++m) {
        const int rbase = bm + wm * 32 + m * 16 + kq * 4;
#pragma unroll
        for (int r = 0; r < 4; ++r) {
            const int row = rbase + r;
            float e0 = emb[(size_t)row * EMB + ds * 2];
            float e1 = emb[(size_t)row * EMB + ds * 2 + 1];
#pragma unroll
            for (int n = 0; n < NB; ++n) {
                const int col = wn * (O / 2) + n * 16 + lr;
                Pd[(size_t)row * O + col] = f2bf(e0 * seg[0][m][n][r] + e1 * seg[1][m][n][r]);
            }
        }
    }
}

// ================= z/r: sum 16 bf16 partials + bias + sigmoid; write z, r*state =================
__global__ void k_zr(const ushort* __restrict__ P, const float* __restrict__ emb,
                     const float* __restrict__ bg, const float* __restrict__ state,
                     float* __restrict__ zbuf, ushort* __restrict__ Hbf,
                     ushort* __restrict__ XTin) {
    __shared__ float es[2][EMB];
    const int t = threadIdx.x;
    if (t < 2 * EMB) es[t >> 4][t & 15] = emb[((size_t)blockIdx.x * 2 + (t >> 4)) * EMB + (t & 15)];
    __syncthreads();
    const int node = blockIdx.x * 2 + (t >> 7);
    const int o = t & 127;
    float v = 0.f;
#pragma unroll
    for (int s = 0; s < 16; ++s) v += bf2f(P[((size_t)s * M + node) * 128 + o]);
    const float* e_ = es[t >> 7];
#pragma unroll
    for (int d = 0; d < EMB; ++d) v += e_[d] * bg[d * 128 + o];
    float sg = 1.f / (1.f + expf(-v));
    if (o < 64) {
        zbuf[node * 64 + o] = sg;
    } else {
        int oo = o - 64;
        ushort bf = f2bf(sg * state[node * 64 + oo]);
        Hbf[(size_t)node * KP + 2 + oo] = bf;
        int b = node / Nn, kn = node % Nn;
        XTin[((size_t)b * XTR + 2 + oo) * NKP + kn] = bf;
    }
}

// ================= final: sum 8 bf16 partials + bias + tanh + GRU blend =================
__global__ void k_final(const ushort* __restrict__ P, const float* __restrict__ emb,
                        const float* __restrict__ bc, const float* __restrict__ zbuf,
                        const float* __restrict__ state, float* __restrict__ out) {
    __shared__ float es[4][EMB];
    const int t = threadIdx.x;
    if (t < 4 * EMB) es[t >> 4][t & 15] = emb[((size_t)blockIdx.x * 4 + (t >> 4)) * EMB + (t & 15)];
    __syncthreads();
    const int node = blockIdx.x * 4 + (t >> 6);
    const int o = t & 63;
    float v = 0.f;
#pragma unroll
    for (int s = 0; s < 8; ++s) v += bf2f(P[((size_t)s * M + node) * 64 + o]);
    const float* e_ = es[t >> 6];
#pragma unroll
    for (int d = 0; d < EMB; ++d) v += e_[d] * bc[d * 64 + o];
    float hc = tanhf(v);
    float z = zbuf[node * 64 + o];
    out[node * 64 + o] = z * state[node * 64 + o] + (1.f - z) * hc;
}

extern "C" void kernel_launch(void* const* d_in, const int* in_sizes, int n_in,
                              void* d_out, int out_size, void* d_ws, size_t ws_size,
                              hipStream_t stream) {
    const float* x      = (const float*)d_in[0];
    const float* state  = (const float*)d_in[1];
    const float* graphs = (const float*)d_in[2];
    const float* emb    = (const float*)d_in[3];
    const float* Wg     = (const float*)d_in[4];
    const float* bg     = (const float*)d_in[5];
    const float* Wc     = (const float*)d_in[6];
    const float* bc     = (const float*)d_in[7];
    float* out = (float*)d_out;

    char* ws = (char*)d_ws;
    ushort* Hbf  = (ushort*)ws;  ws += (size_t)M * KP * 2;                 // 2.25 MB
    ushort* Gbf  = (ushort*)ws;  ws += (size_t)GN * Bb * Nn * NKP * 2;     // 5.32 MB
    ushort* WgT  = (ushort*)ws;  ws += (size_t)2048 * KP * 2;              // 1.44 MB
    ushort* WcT  = (ushort*)ws;  ws += (size_t)1024 * KP * 2;              // 0.72 MB
    ushort* XTin = (ushort*)ws;  ws += (size_t)Bb * XTR * NKP * 2;         // 0.53 MB
    ushort* XTmid= (ushort*)ws;  ws += (size_t)GN * Bb * XTR * NKP * 2;    // 1.06 MB
    ushort* PG   = (ushort*)ws;  ws += (size_t)16 * M * 128 * 2;           // 13.1 MB
    ushort* PC   = (ushort*)ws;  ws += (size_t)8 * M * 64 * 2;             // 3.28 MB
    float*  zb   = (float*)ws;                                             // 0.82 MB

    dim3 hopgrid(25, Bb, GN);

    k_prep<<<3184, 256, 0, stream>>>(graphs, Wg, Wc, x, state, Gbf, WgT, WcT, Hbf, XTin);

    // ---- first meta_dgcn (gates) ----
    k_hop<<<hopgrid, 64, 0, stream>>>(Gbf, XTin, Hbf, XTmid, 66, 0);
    k_hop<<<hopgrid, 64, 0, stream>>>(Gbf, XTmid, Hbf, nullptr, 132, 1);
    k_meta_d16<<<dim3(16, 50), 256, 0, stream>>>(Hbf, WgT, emb, PG);
    k_zr<<<1600, 256, 0, stream>>>(PG, emb, bg, state, zb, Hbf, XTin);

    // ---- second meta_dgcn (candidate) ----
    k_hop<<<hopgrid, 64, 0, stream>>>(Gbf, XTin, Hbf, XTmid, 66, 0);
    k_hop<<<hopgrid, 64, 0, stream>>>(Gbf, XTmid, Hbf, nullptr, 132, 1);
    k_meta_fused<64><<<dim3(8, 50), 256, 0, stream>>>(Hbf, WcT, emb, PC);
    k_final<<<800, 256, 0, stream>>>(PC, emb, bc, zb, state, out);
}